// Round 17
// baseline (1206.330 us; speedup 1.0000x reference)
//
#include <hip/hip_runtime.h>
#include <hip/hip_fp16.h>

typedef _Float16 f16;
typedef _Float16 f16x2 __attribute__((ext_vector_type(2)));
typedef _Float16 f16x4 __attribute__((ext_vector_type(4)));
typedef _Float16 f16x8 __attribute__((ext_vector_type(8)));
typedef float    f32x4 __attribute__((ext_vector_type(4)));
typedef unsigned long long u64t;

#define DEV __device__ __forceinline__

constexpr int B = 32, T = 64, S = 64, H = 512, E = 512, V = 32000;
constexpr int BT = B * T;      // 2048
constexpr int G4 = 4 * H;      // 2048
constexpr int NBLK = 64;       // scan blocks
constexpr int NFEED = 32;      // feeder blocks (1 per batch)

DEV float sigf(float x) { return 1.f / (1.f + expf(-x)); }

#if defined(__has_builtin)
#if __has_builtin(__builtin_amdgcn_global_load_lds)
#define HAVE_GLL 1
#endif
#if __has_builtin(__builtin_amdgcn_fdot2)
#define HAVE_FDOT2 1
#endif
#endif

DEV float dot2f(unsigned a, unsigned b, float c) {
#if HAVE_FDOT2
    return __builtin_amdgcn_fdot2(__builtin_bit_cast(f16x2, a),
                                  __builtin_bit_cast(f16x2, b), c, false);
#else
    f16x2 av = __builtin_bit_cast(f16x2, a);
    f16x2 bv = __builtin_bit_cast(f16x2, b);
    return c + (float)av.x * (float)bv.x + (float)av.y * (float)bv.y;
#endif
}

// relaxed agent-scope = plain sc1 loads/stores (MALL-coherent, no wbl2/inv)
DEV u64t ld_u64_cg(const u64t* p) {
    return __hip_atomic_load(p, __ATOMIC_RELAXED, __HIP_MEMORY_SCOPE_AGENT);
}
DEV unsigned ld_u32_cg(const unsigned* p) {
    return __hip_atomic_load(p, __ATOMIC_RELAXED, __HIP_MEMORY_SCOPE_AGENT);
}
DEV void st_u32_cg(unsigned* p, unsigned v) {
    __hip_atomic_store(p, v, __ATOMIC_RELAXED, __HIP_MEMORY_SCOPE_AGENT);
}

#if HAVE_GLL
DEV void gll16(f16* lds, const f16* g) {
    __builtin_amdgcn_global_load_lds(
        (const __attribute__((address_space(1))) void*)g,
        (__attribute__((address_space(3))) void*)lds, 16, 0, 0);
}
#endif

// ---------------- W_out convert (big, grid-stride) ----------------

__global__ __launch_bounds__(256) void cvt_f16(const float* __restrict__ s,
                                               f16* __restrict__ d, int n4) {
    for (int i = blockIdx.x * blockDim.x + threadIdx.x; i < n4;
         i += gridDim.x * blockDim.x) {
        float4 v = ((const float4*)s)[i];
        f16x4 o = {(f16)v.x, (f16)v.y, (f16)v.z, (f16)v.w};
        ((f16x4*)d)[i] = o;
    }
}

// ---------------- fused prep: all small converts/packs, exact ranges -------
// [0,1024)    cvt W_ih      (262144 float4)
// [1024,3072) cvt enc       (524288 float4)
// [3072,3584) pack_wfrag    (131072 items)
// [3584,3840) pack wattF    (65536 items)   MFMA B-frag order, K=512
// [3840,4224) pack wcombF   (98304 items)   MFMA B-frag order, K=1536
// [4224,5248) gather_x      (262144 items)
// [5248,5312) init_h0+flags (16384 items)

__global__ __launch_bounds__(256) void prep_all(
    const float* __restrict__ W_ih, f16* __restrict__ W_ih_h,
    const float* __restrict__ enc, f16* __restrict__ enc_h,
    const float* __restrict__ W_hh, f16* __restrict__ Wfrag,
    const float* __restrict__ W_att, f16* __restrict__ wattF,
    const float* __restrict__ W_comb, f16* __restrict__ wcombF,
    const int* __restrict__ tok, const float* __restrict__ emb,
    f16* __restrict__ x_h, const float* __restrict__ h0,
    f16* __restrict__ xbuf, unsigned* __restrict__ flags) {
    const int bid = blockIdx.x;
    const int tid = threadIdx.x;
    if (bid < 1024) {
        int i = bid * 256 + tid;
        float4 v = ((const float4*)W_ih)[i];
        f16x4 o = {(f16)v.x, (f16)v.y, (f16)v.z, (f16)v.w};
        ((f16x4*)W_ih_h)[i] = o;
    } else if (bid < 3072) {
        int i = (bid - 1024) * 256 + tid;
        float4 v = ((const float4*)enc)[i];
        f16x4 o = {(f16)v.x, (f16)v.y, (f16)v.z, (f16)v.w};
        ((f16x4*)enc_h)[i] = o;
    } else if (bid < 3584) {
        int id = (bid - 3072) * 256 + tid;  // R6-verified pack_wfrag body
        int lane = id & 63;
        int ks = (id >> 6) & 15;
        int ni = (id >> 10) & 1;
        int n = id >> 11;
        int cl = ni * 16 + (lane & 15);
        int ul = cl >> 2, g = cl & 3;
        int unit = n * 8 + ul;
        int k = ks * 32 + (lane >> 4) * 8;
        const float* src = W_hh + (size_t)(g * 512 + unit) * 512 + k;
        float4 a = *(const float4*)src;
        float4 b = *(const float4*)(src + 4);
        f16x8 o = {(f16)a.x, (f16)a.y, (f16)a.z, (f16)a.w,
                   (f16)b.x, (f16)b.y, (f16)b.z, (f16)b.w};
        *(f16x8*)(Wfrag + (size_t)id * 8) = o;
    } else if (bid < 3840) {
        // wattF[id]: id = (nt*16+ks)*64 + l; value = W_att[nt*16+(l&15)]
        //            [ks*32+(l>>4)*8 + e], nt<64, ks<16
        int id = (bid - 3584) * 256 + tid;
        int l = id & 63;
        int ks = (id >> 6) & 15;
        int nt = id >> 10;
        int j = nt * 16 + (l & 15);
        int k = ks * 32 + (l >> 4) * 8;
        const float* src = W_att + (size_t)j * 512 + k;
        float4 a = *(const float4*)src;
        float4 b = *(const float4*)(src + 4);
        f16x8 o = {(f16)a.x, (f16)a.y, (f16)a.z, (f16)a.w,
                   (f16)b.x, (f16)b.y, (f16)b.z, (f16)b.w};
        *(f16x8*)(wattF + (size_t)id * 8) = o;
    } else if (bid < 4224) {
        // wcombF[id]: id = (nt*48+ks)*64 + l; value = W_comb[nt*16+(l&15)]
        //             [ks*32+(l>>4)*8 + e], nt<32, ks<48
        int id = (bid - 3840) * 256 + tid;
        int l = id & 63;
        int t2 = id >> 6;           // nt*48 + ks
        int ks = t2 % 48;
        int nt = t2 / 48;
        int j = nt * 16 + (l & 15);
        int k = ks * 32 + (l >> 4) * 8;
        const float* src = W_comb + (size_t)j * 1536 + k;
        float4 a = *(const float4*)src;
        float4 b = *(const float4*)(src + 4);
        f16x8 o = {(f16)a.x, (f16)a.y, (f16)a.z, (f16)a.w,
                   (f16)b.x, (f16)b.y, (f16)b.z, (f16)b.w};
        *(f16x8*)(wcombF + (size_t)id * 8) = o;
    } else if (bid < 5248) {
        int id = (bid - 4224) * 256 + tid;  // gather_x body
        int row = id >> 7;
        int e4 = (id & 127) * 4;
        int t = tok[row];
        float4 v = *(const float4*)(emb + (size_t)t * E + e4);
        f16x4 o = {(f16)v.x, (f16)v.y, (f16)v.z, (f16)v.w};
        ((f16x4*)x_h)[id] = o;
    } else {
        int i = (bid - 5248) * 256 + tid;   // init_h0 body
        int nn = i >> 8;
        int bb = (i >> 3) & 31;
        int ul = i & 7;
        xbuf[i] = (f16)h0[bb * 512 + nn * 8 + ul];
        if (i < NBLK) flags[i] = 0u;
    }
}

// ---------------- GEMM (proven): C = A @ W^T (+bias); PERM / MSWAP opts ----

template <bool BIAS, bool B2, bool PERM, bool MSWAP, typename OUT>
__global__ __launch_bounds__(256) void gemm_bt(
    const f16* __restrict__ A, int lda, const f16* __restrict__ W, int ldw,
    OUT* __restrict__ C, int ldc, int K, const float* __restrict__ bias1,
    const float* __restrict__ bias2) {
    __shared__ f16 smA[128 * 32];
    __shared__ f16 smB[128 * 32];
    const int tid = threadIdx.x;
    const int lane = tid & 63;
    const int wv = tid >> 6;
    const int wr = wv >> 1, wc = wv & 1;
    const int m0 = (MSWAP ? blockIdx.x : blockIdx.y) * 128;
    const int n0 = (MSWAP ? blockIdx.y : blockIdx.x) * 128;
    const int ar0 = tid >> 2;
    const int kq = (tid & 3) * 8;

    f32x4 acc[4][4];
#pragma unroll
    for (int m = 0; m < 4; m++)
#pragma unroll
        for (int n = 0; n < 4; n++) acc[m][n] = {0.f, 0.f, 0.f, 0.f};

    const int arow = wr * 64 + (lane & 15);
    const int brow = wc * 64 + (lane & 15);
    const int kk = (lane >> 4) * 8;

    const int ksteps = K >> 5;
    for (int s = 0; s < ksteps; ++s) {
        const int k0 = s * 32;
        const f16* Ag = A + (size_t)(m0 + ar0) * lda + k0 + kq;
        const f16* Wg = W + (size_t)(n0 + ar0) * ldw + k0 + kq;
#if HAVE_GLL
        __syncthreads();
        gll16(smA + wv * 512, Ag);
        gll16(smA + 2048 + wv * 512, Ag + (size_t)64 * lda);
        gll16(smB + wv * 512, Wg);
        gll16(smB + 2048 + wv * 512, Wg + (size_t)64 * ldw);
        __syncthreads();
#else
        uint4 va0 = *(const uint4*)Ag;
        uint4 va1 = *(const uint4*)(Ag + (size_t)64 * lda);
        uint4 vb0 = *(const uint4*)Wg;
        uint4 vb1 = *(const uint4*)(Wg + (size_t)64 * ldw);
        __syncthreads();
        *(uint4*)(smA + tid * 8) = va0;
        *(uint4*)(smA + (tid + 256) * 8) = va1;
        *(uint4*)(smB + tid * 8) = vb0;
        *(uint4*)(smB + (tid + 256) * 8) = vb1;
        __syncthreads();
#endif
        f16x8 af[4], bfr[4];
#pragma unroll
        for (int m = 0; m < 4; m++)
            af[m] = *(const f16x8*)(smA + (arow + m * 16) * 32 + kk);
#pragma unroll
        for (int n = 0; n < 4; n++)
            bfr[n] = *(const f16x8*)(smB + (brow + n * 16) * 32 + kk);
#pragma unroll
        for (int m = 0; m < 4; m++)
#pragma unroll
            for (int n = 0; n < 4; n++)
                acc[m][n] = __builtin_amdgcn_mfma_f32_16x16x32_f16(
                    af[m], bfr[n], acc[m][n], 0, 0, 0);
    }

    const int fr = lane & 15, fq = lane >> 4;
#pragma unroll
    for (int m = 0; m < 4; m++) {
        const int row0 = m0 + wr * 64 + m * 16 + fq * 4;
#pragma unroll
        for (int n = 0; n < 4; n++) {
            const int col = n0 + wc * 64 + n * 16 + fr;
            float bb = 0.f;
            if (BIAS) bb += bias1[col];
            if (B2) bb += bias2[col];
            int nb = 0, cl = 0;
            if (PERM) {
                int g = col >> 9;
                int unit = col & 511;
                nb = unit >> 3;
                cl = ((unit & 7) << 2) | g;
            }
#pragma unroll
            for (int r = 0; r < 4; r++) {
                float v = acc[m][n][r] + bb;
                if (PERM) {
                    int bt = row0 + r;
                    int b_ = bt >> 6, tt = bt & 63;
                    C[((size_t)(tt * 64 + nb) * 32 + b_) * 32 + cl] = (OUT)v;
                } else {
                    C[(size_t)(row0 + r) * ldc + col] = (OUT)v;
                }
            }
        }
    }
}

// ---------------- mega96m: scan (0-63) + MFMA-feeders (64-95) --------------
// Scan: R14/R15/R16-verified, byte-identical.
// Feeders (1/batch, 8-step chunks): h8 + applied live in LDS mg[16][1544]
//   (cols 0:512 = h, 512:1536 = applied; rows 8:15 garbage-but-harmless since
//   MFMA C rows depend only on same A row). Phases per chunk:
//   1) q = h @ W_att^T   : MFMA, B-frags from wattF   (16 nt x 16 ks / wave)
//   2) w[s] = q . enc    : scalar (R15-verified)
//   3) applied = w @ enc : scalar (R15-verified), writes mg[.][512:]
//   4) outs = tanh([h|ap] @ W_comb^T + b_comb): MFMA, B-frags from wcombF
//   outs written with plain stores (consumed by a separate kernel).
// NO logits consumers in-kernel (R13/R15 lesson).

constexpr int LDS_BYTES = 84480;  // feeder: mg 49408 + q16 33024 + wsch 2048

__global__ __launch_bounds__(256, 1) void mega96m(
    const float* __restrict__ gxp, const f16* __restrict__ Wfrag,
    const float* __restrict__ c0, f16* __restrict__ xbuf,
    unsigned* __restrict__ flags, f16* __restrict__ hseq,
    float* __restrict__ hout, float* __restrict__ cout,
    const f16* __restrict__ wattF, const f16* __restrict__ enc_h,
    const f16* __restrict__ wcombF, const float* __restrict__ b_comb,
    f16* __restrict__ outsP) {
    __shared__ __align__(16) char lds[LDS_BYTES];
    const int bid = blockIdx.x;
    const int tid = threadIdx.x;
    const int lane = tid & 63, wv = tid >> 6;

    if (bid < NBLK) {
        // ================= SCAN (R14-verified) =================
        const int n = bid;
        const int mi = wv >> 1, ni = wv & 1;
        f16(*hst)[520] = (f16(*)[520])lds;
        float(*gl)[32] = (float(*)[32])(lds + 33280);

        f16x8 bf[16];
        const f16* wbase =
            Wfrag + (size_t)((n * 2 + ni) * 16) * 512 + lane * 8;
#pragma unroll
        for (int ks = 0; ks < 16; ks++)
            bf[ks] = *(const f16x8*)(wbase + ks * 512);

        const int bb = tid >> 3, ul = tid & 7;
        const int unit = n * 8 + ul;
        float c = c0[bb * 512 + unit];
        float h = 0.f;

        const int sb = (tid & 63) >> 1;
        const int su0 = (tid & 1) * 4;
        const int arow = mi * 16 + (lane & 15);
        const int kcol0 = (lane >> 4) * 8;
        const int fr = lane & 15, fq = lane >> 4;

        for (int t = 0; t < T; ++t) {
            float4 gx4 = *(const float4*)(gxp +
                ((size_t)(t * NBLK + n) * 32 + bb) * 32 + ul * 4);
            for (;;) {
                unsigned v = ld_u32_cg(flags + lane);
                if (__all(v >= (unsigned)t)) break;
                __builtin_amdgcn_s_sleep(1);
            }
            asm volatile("" ::: "memory");
            const u64t* src = (const u64t*)(xbuf + (t & 1) * (B * H));
            u64t v[16];
#pragma unroll
            for (int i = 0; i < 16; i++) v[i] = ld_u64_cg(src + i * 256 + tid);
#pragma unroll
            for (int i = 0; i < 16; i++) {
                int np = i * 4 + wv;
                *(u64t*)(&hst[sb][np * 8 + su0]) = v[i];
            }
            __syncthreads();
            f32x4 acc0 = {0.f, 0.f, 0.f, 0.f}, acc1 = {0.f, 0.f, 0.f, 0.f};
#pragma unroll
            for (int ks = 0; ks < 16; ks++) {
                f16x8 af = *(const f16x8*)(&hst[arow][ks * 32 + kcol0]);
                if (ks & 1)
                    acc1 = __builtin_amdgcn_mfma_f32_16x16x32_f16(af, bf[ks],
                                                                  acc1, 0, 0, 0);
                else
                    acc0 = __builtin_amdgcn_mfma_f32_16x16x32_f16(af, bf[ks],
                                                                  acc0, 0, 0, 0);
            }
#pragma unroll
            for (int r = 0; r < 4; r++)
                gl[mi * 16 + fq * 4 + r][ni * 16 + fr] = acc0[r] + acc1[r];
            __syncthreads();
            float4 gv = *(const float4*)&gl[bb][ul * 4];
            float gi = gv.x + gx4.x;
            float gf = gv.y + gx4.y;
            float gg = gv.z + gx4.z;
            float go = gv.w + gx4.w;
            c = sigf(gf) * c + sigf(gi) * tanhf(gg);
            h = sigf(go) * tanhf(c);
            f16 hh = (f16)h;
            unsigned hv = (unsigned)__builtin_bit_cast(unsigned short, hh);
            unsigned other = (unsigned)__shfl_xor((int)hv, 1);
            unsigned packed = hv | (other << 16);
            f16* xn = xbuf + ((t + 1) & 1) * (B * H);
            if ((ul & 1) == 0)
                st_u32_cg((unsigned*)(xn + n * 256 + bb * 8 + ul), packed);
            if (t < T - 1) {
                asm volatile("s_waitcnt vmcnt(0)" ::: "memory");
                __syncthreads();
                if (tid == 0) st_u32_cg(flags + n, (unsigned)(t + 1));
            } else {
                __syncthreads();
            }
            if ((ul & 1) == 0)
                st_u32_cg((unsigned*)(hseq + ((size_t)t * 32 + bb) * 512 +
                                      unit), packed);
        }
        asm volatile("s_waitcnt vmcnt(0)" ::: "memory");
        __syncthreads();
        if (tid == 0) st_u32_cg(flags + n, 66u);
        hout[bb * 512 + unit] = h;
        cout[bb * 512 + unit] = c;

    } else {
        // ========== FEEDER (one batch b), MFMA q/outs ==========
        const int b = bid - NBLK;
        f16(*mg)[1544] = (f16(*)[1544])lds;             // 49408 B: [h|applied]
        f16(*q16)[1032] = (f16(*)[1032])(lds + 49408);  // 33024 B
        float(*wsch)[64] = (float(*)[64])(lds + 82432); // 2048 B
        const unsigned* hseqU = (const unsigned*)hseq;
        const int fr = lane & 15, fq = lane >> 4;

        for (int g = 0; g < 8; ++g) {
            const unsigned target = (unsigned)(g * 8 + 9);
            for (;;) {
                unsigned v = ld_u32_cg(flags + lane);
                if (__all(v >= target)) break;
                __builtin_amdgcn_s_sleep(4);
            }
            asm volatile("" ::: "memory");
            __syncthreads();  // prev chunk's phase-4 mg reads complete
            // phase 0: load h(8 steps) into mg[0:8][0:512]
#pragma unroll
            for (int i = 0; i < 8; ++i)
                ((unsigned*)&mg[i][0])[tid] = ld_u32_cg(
                    hseqU + ((size_t)(g * 8 + i) * 32 + b) * 256 + tid);
            __syncthreads();
            // phase 1: q = h @ W_att^T (MFMA; 16 nt per wave, K=512)
            for (int qq = 0; qq < 16; ++qq) {
                int nt = wv * 16 + qq;
                const f16* wp = wattF + (size_t)(nt * 16) * 512 + lane * 8;
                f32x4 acc = {0.f, 0.f, 0.f, 0.f};
#pragma unroll
                for (int ks = 0; ks < 16; ++ks) {
                    f16x8 af = *(const f16x8*)&mg[fr][ks * 32 + fq * 8];
                    f16x8 bfr = *(const f16x8*)(wp + ks * 512);
                    acc = __builtin_amdgcn_mfma_f32_16x16x32_f16(af, bfr, acc,
                                                                 0, 0, 0);
                }
#pragma unroll
                for (int r = 0; r < 4; ++r)
                    q16[fq * 4 + r][nt * 16 + fr] = (f16)acc[r];
            }
            __syncthreads();
            // phase 2: w[s] = q . enc[b][s] (scalar, R15-verified)
            {
                int s = tid >> 2, part = tid & 3;
                const unsigned* encp =
                    (const unsigned*)enc_h + ((size_t)(b * 64 + s)) * 512 +
                    part * 128;
                float wa[8];
#pragma unroll
                for (int i = 0; i < 8; ++i) wa[i] = 0.f;
                for (int it = 0; it < 32; ++it) {
                    uint4 e4 = *(const uint4*)&encp[it * 4];
#pragma unroll
                    for (int i = 0; i < 8; ++i) {
                        const unsigned* qp =
                            (const unsigned*)&q16[i][0] + part * 128;
                        uint4 q4 = *(const uint4*)&qp[it * 4];
                        wa[i] = dot2f(q4.x, e4.x, wa[i]);
                        wa[i] = dot2f(q4.y, e4.y, wa[i]);
                        wa[i] = dot2f(q4.z, e4.z, wa[i]);
                        wa[i] = dot2f(q4.w, e4.w, wa[i]);
                    }
                }
#pragma unroll
                for (int i = 0; i < 8; ++i) {
                    float w = wa[i];
                    w += __shfl_xor(w, 1);
                    w += __shfl_xor(w, 2);
                    if (part == 0) wsch[i][s] = w;
                }
            }
            __syncthreads();
            // phase 3: applied = w @ enc (scalar, R15-verified) -> mg[.][512:]
            {
                float a0[8], a1[8], a2[8], a3[8];
#pragma unroll
                for (int i = 0; i < 8; ++i) {
                    a0[i] = 0.f; a1[i] = 0.f; a2[i] = 0.f; a3[i] = 0.f;
                }
                for (int s2 = 0; s2 < 64; ++s2) {
                    const f16* er =
                        enc_h + ((size_t)(b * 64 + s2)) * 1024 + tid;
                    float e0 = (float)er[0];
                    float e1 = (float)er[256];
                    float e2 = (float)er[512];
                    float e3 = (float)er[768];
#pragma unroll
                    for (int i = 0; i < 8; ++i) {
                        float w = wsch[i][s2];
                        a0[i] += w * e0;
                        a1[i] += w * e1;
                        a2[i] += w * e2;
                        a3[i] += w * e3;
                    }
                }
#pragma unroll
                for (int i = 0; i < 8; ++i) {
                    mg[i][512 + tid] = (f16)a0[i];
                    mg[i][768 + tid] = (f16)a1[i];
                    mg[i][1024 + tid] = (f16)a2[i];
                    mg[i][1280 + tid] = (f16)a3[i];
                }
            }
            __syncthreads();
            // phase 4: outs = tanh([h|applied] @ W_comb^T + b_comb) (MFMA)
            for (int qq = 0; qq < 8; ++qq) {
                int nt = wv * 8 + qq;
                const f16* wp = wcombF + (size_t)(nt * 48) * 512 + lane * 8;
                f32x4 acc = {0.f, 0.f, 0.f, 0.f};
                for (int ks = 0; ks < 48; ++ks) {
                    f16x8 af = *(const f16x8*)&mg[fr][ks * 32 + fq * 8];
                    f16x8 bfr = *(const f16x8*)(wp + ks * 512);
                    acc = __builtin_amdgcn_mfma_f32_16x16x32_f16(af, bfr, acc,
                                                                 0, 0, 0);
                }
#pragma unroll
                for (int r = 0; r < 4; ++r) {
                    int t = fq * 4 + r;
                    if (t < 8) {
                        int col = nt * 16 + fr;
                        float v = tanhf(acc[r] + b_comb[col]);
                        outsP[((size_t)(b * 64 + g * 8 + t)) * 512 + col] =
                            (f16)v;
                    }
                }
            }
            // top-of-loop barrier protects mg for next chunk
        }
        // outs stores flushed at kernel-boundary release
    }
}

// ---------------- launcher ----------------

extern "C" void kernel_launch(void* const* d_in, const int* in_sizes, int n_in,
                              void* d_out, int out_size, void* d_ws,
                              size_t ws_size, hipStream_t stream) {
    const int* tok = (const int*)d_in[0];
    const float* enc = (const float*)d_in[1];
    const float* h0 = (const float*)d_in[2];
    const float* c0 = (const float*)d_in[3];
    const float* emb = (const float*)d_in[4];
    const float* W_ih = (const float*)d_in[5];
    const float* W_hh = (const float*)d_in[6];
    const float* b_ih = (const float*)d_in[7];
    const float* b_hh = (const float*)d_in[8];
    const float* W_att = (const float*)d_in[9];
    const float* W_comb = (const float*)d_in[10];
    const float* b_comb = (const float*)d_in[11];
    const float* W_out = (const float*)d_in[12];
    const float* b_out = (const float*)d_in[13];

    float* out_logits = (float*)d_out;
    float* out_h = out_logits + (size_t)BT * V;
    float* out_c = out_h + (size_t)B * H;

    char* p = (char*)d_ws;
    auto alloc = [&](size_t bytes) -> void* {
        void* r = (void*)p;
        p += (bytes + 255) & ~(size_t)255;
        return r;
    };
    f16* W_ih_h = (f16*)alloc((size_t)G4 * E * 2);           // 2MB
    f16* Wfrag = (f16*)alloc((size_t)NBLK * 2 * 16 * 64 * 8 * 2);  // 2MB
    f16* W_out_h = (f16*)alloc((size_t)V * 512 * 2);         // 32MB
    f16* enc_h = (f16*)alloc((size_t)B * S * 1024 * 2);      // 4MB
    f16* wattF = (f16*)alloc((size_t)64 * 16 * 64 * 8 * 2);  // 1MB
    f16* wcombF = (f16*)alloc((size_t)32 * 48 * 64 * 8 * 2); // 1.5MB
    f16* x_h = (f16*)alloc((size_t)BT * E * 2);              // 2MB
    float* gxp = (float*)alloc((size_t)T * NBLK * 32 * 32 * 4);  // 16MB
    f16* hseq = (f16*)alloc((size_t)T * B * 512 * 2);        // 2MB
    f16* outsP = (f16*)alloc((size_t)BT * 512 * 2);          // 2MB (bt-major)
    f16* xbuf = (f16*)alloc((size_t)2 * B * H * 2);          // 128KB
    unsigned* flags = (unsigned*)alloc(256);

    // fused small preps (exact ranges) + big W_out cvt
    prep_all<<<5312, 256, 0, stream>>>(W_ih, W_ih_h, enc, enc_h, W_hh, Wfrag,
                                       W_att, wattF, W_comb, wcombF, tok, emb,
                                       x_h, h0, xbuf, flags);
    cvt_f16<<<2048, 256, 0, stream>>>(W_out, W_out_h, V * 512 / 4);

    // gates_x = x @ W_ih^T + b_ih + b_hh, permuted for the scan
    gemm_bt<true, true, true, false, float><<<dim3(16, 16), 256, 0, stream>>>(
        x_h, E, W_ih_h, E, gxp, 0, E, b_ih, b_hh);

    // fused scan + MFMA attention feeders (hidden in scan's idle shadow)
    mega96m<<<NBLK + NFEED, 256, 0, stream>>>(gxp, Wfrag, c0, xbuf, flags,
                                              hseq, out_h, out_c, wattF,
                                              enc_h, wcombF, b_comb, outsP);

    // logits = outs @ W_out^T + b_out   [2048 x 32000] fp32 -> d_out
    // separate kernel (R13/R15 lesson); MSWAP for W-panel L2 reuse
    gemm_bt<true, false, false, true, float>
        <<<dim3(16, 250), 256, 0, stream>>>(outsP, 512, W_out_h, 512,
                                            out_logits, V, 512, b_out,
                                            nullptr);
}

// Round 18
// 543.315 us; speedup vs baseline: 2.2203x; 2.2203x over previous
//
#include <hip/hip_runtime.h>
#include <hip/hip_fp16.h>

typedef _Float16 f16;
typedef _Float16 f16x4 __attribute__((ext_vector_type(4)));
typedef _Float16 f16x8 __attribute__((ext_vector_type(8)));
typedef float    f32x4 __attribute__((ext_vector_type(4)));
typedef unsigned long long u64t;

#define DEV __device__ __forceinline__

constexpr int B = 32, T = 64, S = 64, H = 512, E = 512, V = 32000;
constexpr int BT = B * T;      // 2048
constexpr int G4 = 4 * H;      // 2048
constexpr int NBLK = 64;       // scan blocks; each owns 8 h-units

DEV float sigf(float x) { return 1.f / (1.f + expf(-x)); }

#if defined(__has_builtin)
#if __has_builtin(__builtin_amdgcn_global_load_lds)
#define HAVE_GLL 1
#endif
#endif

// relaxed agent-scope ops: plain sc1 loads/stores, NO buffer_wbl2/inv
DEV u64t ld_u64_cg(const u64t* p) {
    return __hip_atomic_load(p, __ATOMIC_RELAXED, __HIP_MEMORY_SCOPE_AGENT);
}
DEV unsigned ld_u32_cg(const unsigned* p) {
    return __hip_atomic_load(p, __ATOMIC_RELAXED, __HIP_MEMORY_SCOPE_AGENT);
}
DEV void st_u32_cg(unsigned* p, unsigned v) {
    __hip_atomic_store(p, v, __ATOMIC_RELAXED, __HIP_MEMORY_SCOPE_AGENT);
}

#if HAVE_GLL
DEV void gll16(f16* lds, const f16* g) {
    __builtin_amdgcn_global_load_lds(
        (const __attribute__((address_space(1))) void*)g,
        (__attribute__((address_space(3))) void*)lds, 16, 0, 0);
}
#endif

// ---------------- W_out convert (big, grid-stride) ----------------

__global__ __launch_bounds__(256) void cvt_f16(const float* __restrict__ s,
                                               f16* __restrict__ d, int n4) {
    for (int i = blockIdx.x * blockDim.x + threadIdx.x; i < n4;
         i += gridDim.x * blockDim.x) {
        float4 v = ((const float4*)s)[i];
        f16x4 o = {(f16)v.x, (f16)v.y, (f16)v.z, (f16)v.w};
        ((f16x4*)d)[i] = o;
    }
}

// ---------------- fused prep: all small converts/packs, exact ranges -------
// [0,1024)     cvt W_ih    (262144 float4)
// [1024,1536)  cvt W_att   (131072 float4)
// [1536,2304)  cvt W_comb  (196608 float4)
// [2304,2816)  pack_wfrag  (131072 items)
// [2816,3840)  gather_x    (262144 items)
// [3840,3904)  init_h0     (16384 items) + flags

__global__ __launch_bounds__(256) void prep_all(
    const float* __restrict__ W_ih, f16* __restrict__ W_ih_h,
    const float* __restrict__ W_att, f16* __restrict__ W_att_h,
    const float* __restrict__ W_comb, f16* __restrict__ W_comb_h,
    const float* __restrict__ W_hh, f16* __restrict__ Wfrag,
    const int* __restrict__ tok, const float* __restrict__ emb,
    f16* __restrict__ x_h, const float* __restrict__ h0,
    f16* __restrict__ xbuf, unsigned* __restrict__ flags) {
    const int bid = blockIdx.x;
    const int tid = threadIdx.x;
    if (bid < 1024) {
        int i = bid * 256 + tid;
        float4 v = ((const float4*)W_ih)[i];
        f16x4 o = {(f16)v.x, (f16)v.y, (f16)v.z, (f16)v.w};
        ((f16x4*)W_ih_h)[i] = o;
    } else if (bid < 1536) {
        int i = (bid - 1024) * 256 + tid;
        float4 v = ((const float4*)W_att)[i];
        f16x4 o = {(f16)v.x, (f16)v.y, (f16)v.z, (f16)v.w};
        ((f16x4*)W_att_h)[i] = o;
    } else if (bid < 2304) {
        int i = (bid - 1536) * 256 + tid;
        float4 v = ((const float4*)W_comb)[i];
        f16x4 o = {(f16)v.x, (f16)v.y, (f16)v.z, (f16)v.w};
        ((f16x4*)W_comb_h)[i] = o;
    } else if (bid < 2816) {
        int id = (bid - 2304) * 256 + tid;  // R6-verified pack_wfrag body
        int lane = id & 63;
        int ks = (id >> 6) & 15;
        int ni = (id >> 10) & 1;
        int n = id >> 11;
        int cl = ni * 16 + (lane & 15);
        int ul = cl >> 2, g = cl & 3;
        int unit = n * 8 + ul;
        int k = ks * 32 + (lane >> 4) * 8;
        const float* src = W_hh + (size_t)(g * 512 + unit) * 512 + k;
        float4 a = *(const float4*)src;
        float4 b = *(const float4*)(src + 4);
        f16x8 o = {(f16)a.x, (f16)a.y, (f16)a.z, (f16)a.w,
                   (f16)b.x, (f16)b.y, (f16)b.z, (f16)b.w};
        *(f16x8*)(Wfrag + (size_t)id * 8) = o;
    } else if (bid < 3840) {
        int id = (bid - 2816) * 256 + tid;  // gather_x body
        int row = id >> 7;
        int e4 = (id & 127) * 4;
        int t = tok[row];
        float4 v = *(const float4*)(emb + (size_t)t * E + e4);
        f16x4 o = {(f16)v.x, (f16)v.y, (f16)v.z, (f16)v.w};
        ((f16x4*)x_h)[id] = o;
    } else {
        int i = (bid - 3840) * 256 + tid;   // init_h0 body
        int nn = i >> 8;
        int bb = (i >> 3) & 31;
        int ul = i & 7;
        xbuf[i] = (f16)h0[bb * 512 + nn * 8 + ul];
        if (i < NBLK) flags[i] = 0u;
    }
}

// ---------------- GEMM (R11-verified): C = A @ W^T (+bias, +tanh) ----------
// 128x128 tile, BK=32, 256 threads = 4 waves, mfma_f32_16x16x32_f16,
// global_load_lds staging. PERM: permuted gates output. MSWAP: m-tile on
// blockIdx.x so dispatch-adjacent blocks share the W panel (logits GEMM).

template <bool BIAS, bool B2, bool TANH, bool PERM, bool MSWAP, typename OUT>
__global__ __launch_bounds__(256) void gemm_bt(
    const f16* __restrict__ A, int lda, const f16* __restrict__ W, int ldw,
    OUT* __restrict__ C, int ldc, int K, const float* __restrict__ bias1,
    const float* __restrict__ bias2) {
    __shared__ f16 smA[128 * 32];
    __shared__ f16 smB[128 * 32];
    const int tid = threadIdx.x;
    const int lane = tid & 63;
    const int wv = tid >> 6;
    const int wr = wv >> 1, wc = wv & 1;
    const int m0 = (MSWAP ? blockIdx.x : blockIdx.y) * 128;
    const int n0 = (MSWAP ? blockIdx.y : blockIdx.x) * 128;
    const int ar0 = tid >> 2;
    const int kq = (tid & 3) * 8;

    f32x4 acc[4][4];
#pragma unroll
    for (int m = 0; m < 4; m++)
#pragma unroll
        for (int n = 0; n < 4; n++) acc[m][n] = {0.f, 0.f, 0.f, 0.f};

    const int arow = wr * 64 + (lane & 15);
    const int brow = wc * 64 + (lane & 15);
    const int kk = (lane >> 4) * 8;

    const int ksteps = K >> 5;
    for (int s = 0; s < ksteps; ++s) {
        const int k0 = s * 32;
        const f16* Ag = A + (size_t)(m0 + ar0) * lda + k0 + kq;
        const f16* Wg = W + (size_t)(n0 + ar0) * ldw + k0 + kq;
#if HAVE_GLL
        __syncthreads();
        gll16(smA + wv * 512, Ag);
        gll16(smA + 2048 + wv * 512, Ag + (size_t)64 * lda);
        gll16(smB + wv * 512, Wg);
        gll16(smB + 2048 + wv * 512, Wg + (size_t)64 * ldw);
        __syncthreads();
#else
        uint4 va0 = *(const uint4*)Ag;
        uint4 va1 = *(const uint4*)(Ag + (size_t)64 * lda);
        uint4 vb0 = *(const uint4*)Wg;
        uint4 vb1 = *(const uint4*)(Wg + (size_t)64 * ldw);
        __syncthreads();
        *(uint4*)(smA + tid * 8) = va0;
        *(uint4*)(smA + (tid + 256) * 8) = va1;
        *(uint4*)(smB + tid * 8) = vb0;
        *(uint4*)(smB + (tid + 256) * 8) = vb1;
        __syncthreads();
#endif
        f16x8 af[4], bfr[4];
#pragma unroll
        for (int m = 0; m < 4; m++)
            af[m] = *(const f16x8*)(smA + (arow + m * 16) * 32 + kk);
#pragma unroll
        for (int n = 0; n < 4; n++)
            bfr[n] = *(const f16x8*)(smB + (brow + n * 16) * 32 + kk);
#pragma unroll
        for (int m = 0; m < 4; m++)
#pragma unroll
            for (int n = 0; n < 4; n++)
                acc[m][n] = __builtin_amdgcn_mfma_f32_16x16x32_f16(
                    af[m], bfr[n], acc[m][n], 0, 0, 0);
    }

    const int fr = lane & 15, fq = lane >> 4;
#pragma unroll
    for (int m = 0; m < 4; m++) {
        const int row0 = m0 + wr * 64 + m * 16 + fq * 4;
#pragma unroll
        for (int n = 0; n < 4; n++) {
            const int col = n0 + wc * 64 + n * 16 + fr;
            float bb = 0.f;
            if (BIAS) bb += bias1[col];
            if (B2) bb += bias2[col];
            int nb = 0, cl = 0;
            if (PERM) {
                int g = col >> 9;
                int unit = col & 511;
                nb = unit >> 3;
                cl = ((unit & 7) << 2) | g;
            }
#pragma unroll
            for (int r = 0; r < 4; r++) {
                float v = acc[m][n][r] + bb;
                if (TANH) v = tanhf(v);
                if (PERM) {
                    int bt = row0 + r;
                    int b_ = bt >> 6, tt = bt & 63;
                    C[((size_t)(tt * 64 + nb) * 32 + b_) * 32 + cl] = (OUT)v;
                } else {
                    C[(size_t)(row0 + r) * ldc + col] = (OUT)v;
                }
            }
        }
    }
}

// ---------------- persistent-W LSTM scan (R6/R11-verified, 252us) ----------
// 64 blocks x 256 threads. Block n owns h-units [n*8, n*8+8).
// xbuf[2][64 n][32 bb][8 ul] f16 block-major exchange; flags[64].
// Reader: poll 64 flags (1 load/lane), ONE cooperative burst read (16 u64
// coalesced sc1 loads/thread, one MALL RTT) -> LDS hst[32][520] -> MFMA.
// Writer: h stores (sc1) -> vmcnt(0) -> syncthreads -> flag store.
// merged store after the flag (off critical path).

__global__ __launch_bounds__(256, 1) void lstm_scan6(
    const float* __restrict__ gxp, const f16* __restrict__ Wfrag,
    const float* __restrict__ c0, f16* __restrict__ xbuf,
    unsigned* __restrict__ flags, f16* __restrict__ merged,
    float* __restrict__ hout, float* __restrict__ cout) {
    const int n = blockIdx.x;
    const int tid = threadIdx.x;
    const int lane = tid & 63, wv = tid >> 6;
    const int mi = wv >> 1, ni = wv & 1;
    __shared__ f16 hst[32][520];    // staged h, +8 f16 row pad
    __shared__ float gl[32][32];

    // persistent B-fragments (the block's W_hh slice)
    f16x8 bf[16];
    const f16* wbase = Wfrag + (size_t)((n * 2 + ni) * 16) * 512 + lane * 8;
#pragma unroll
    for (int ks = 0; ks < 16; ks++) bf[ks] = *(const f16x8*)(wbase + ks * 512);

    const int bb = tid >> 3, ul = tid & 7;   // (batch, unit-local)
    const int unit = n * 8 + ul;
    float c = c0[bb * 512 + unit];
    float h = 0.f;

    const int sb = (tid & 63) >> 1;
    const int su0 = (tid & 1) * 4;
    const int arow = mi * 16 + (lane & 15);
    const int kcol0 = (lane >> 4) * 8;
    const int fr = lane & 15, fq = lane >> 4;

    for (int t = 0; t < T; ++t) {
        float4 gx4 = *(const float4*)(gxp +
                                      ((size_t)(t * NBLK + n) * 32 + bb) * 32 +
                                      ul * 4);
        for (;;) {
            unsigned v = ld_u32_cg(flags + lane);
            if (__all(v >= (unsigned)t)) break;
            __builtin_amdgcn_s_sleep(1);
        }
        asm volatile("" ::: "memory");  // no load hoisting above the poll
        const u64t* src = (const u64t*)(xbuf + (t & 1) * (B * H));
        u64t v[16];
#pragma unroll
        for (int i = 0; i < 16; i++) v[i] = ld_u64_cg(src + i * 256 + tid);
#pragma unroll
        for (int i = 0; i < 16; i++) {
            int np = i * 4 + wv;
            *(u64t*)(&hst[sb][np * 8 + su0]) = v[i];
        }
        __syncthreads();
        f32x4 acc0 = {0.f, 0.f, 0.f, 0.f}, acc1 = {0.f, 0.f, 0.f, 0.f};
#pragma unroll
        for (int ks = 0; ks < 16; ks++) {
            f16x8 af = *(const f16x8*)(&hst[arow][ks * 32 + kcol0]);
            if (ks & 1)
                acc1 = __builtin_amdgcn_mfma_f32_16x16x32_f16(af, bf[ks], acc1,
                                                              0, 0, 0);
            else
                acc0 = __builtin_amdgcn_mfma_f32_16x16x32_f16(af, bf[ks], acc0,
                                                              0, 0, 0);
        }
#pragma unroll
        for (int r = 0; r < 4; r++)
            gl[mi * 16 + fq * 4 + r][ni * 16 + fr] = acc0[r] + acc1[r];
        __syncthreads();
        float4 gv = *(const float4*)&gl[bb][ul * 4];
        float gi = gv.x + gx4.x;
        float gf = gv.y + gx4.y;
        float gg = gv.z + gx4.z;
        float go = gv.w + gx4.w;
        c = sigf(gf) * c + sigf(gi) * tanhf(gg);
        h = sigf(go) * tanhf(c);
        f16 hh = (f16)h;
        unsigned hv = (unsigned)__builtin_bit_cast(unsigned short, hh);
        unsigned other = (unsigned)__shfl_xor((int)hv, 1);
        f16* xn = xbuf + ((t + 1) & 1) * (B * H);
        if ((ul & 1) == 0) {
            st_u32_cg((unsigned*)(xn + n * 256 + bb * 8 + ul),
                      hv | (other << 16));
        }
        if (t < T - 1) {
            asm volatile("s_waitcnt vmcnt(0)" ::: "memory");
            __syncthreads();
            if (tid == 0) st_u32_cg(flags + n, (unsigned)(t + 1));
        } else {
            __syncthreads();
        }
        // off the critical path
        merged[(size_t)(bb * 64 + t) * 1536 + unit] = hh;
    }
    hout[bb * 512 + unit] = h;
    cout[bb * 512 + unit] = c;
}

// ---------------- fused attention (R11-verified) ----------------

__global__ __launch_bounds__(256) void attn_apply(const float* __restrict__ q,
                                                  const float* __restrict__ enc,
                                                  f16* __restrict__ merged) {
    const int bt = blockIdx.x;
    const int b = bt >> 6;
    const int tid = threadIdx.x;
    __shared__ float qs[1024];
    __shared__ float ws[64];

    const float* qrow = q + (size_t)bt * 1024;
    *(float4*)(qs + tid * 4) = *(const float4*)(qrow + tid * 4);
    __syncthreads();

    const int wv = tid >> 6, lane = tid & 63;
    const float* encb = enc + (size_t)b * S * 1024;
    for (int s = wv * 16; s < wv * 16 + 16; ++s) {
        const float* er = encb + (size_t)s * 1024;
        float p = 0.f;
#pragma unroll
        for (int i = 0; i < 16; ++i) p += qs[lane + 64 * i] * er[lane + 64 * i];
#pragma unroll
        for (int off = 32; off; off >>= 1) p += __shfl_xor(p, off);
        if (lane == 0) ws[s] = p;
    }
    __syncthreads();

    float a0 = 0.f, a1 = 0.f, a2 = 0.f, a3 = 0.f;
    for (int s = 0; s < 64; ++s) {
        float w = ws[s];
        const float* er = encb + (size_t)s * 1024;
        a0 += w * er[tid];
        a1 += w * er[tid + 256];
        a2 += w * er[tid + 512];
        a3 += w * er[tid + 768];
    }
    f16* mrow = merged + (size_t)bt * 1536 + 512;
    mrow[tid] = (f16)a0;
    mrow[tid + 256] = (f16)a1;
    mrow[tid + 512] = (f16)a2;
    mrow[tid + 768] = (f16)a3;
}

// ---------------- launcher ----------------

extern "C" void kernel_launch(void* const* d_in, const int* in_sizes, int n_in,
                              void* d_out, int out_size, void* d_ws,
                              size_t ws_size, hipStream_t stream) {
    const int* tok = (const int*)d_in[0];
    const float* enc = (const float*)d_in[1];
    const float* h0 = (const float*)d_in[2];
    const float* c0 = (const float*)d_in[3];
    const float* emb = (const float*)d_in[4];
    const float* W_ih = (const float*)d_in[5];
    const float* W_hh = (const float*)d_in[6];
    const float* b_ih = (const float*)d_in[7];
    const float* b_hh = (const float*)d_in[8];
    const float* W_att = (const float*)d_in[9];
    const float* W_comb = (const float*)d_in[10];
    const float* b_comb = (const float*)d_in[11];
    const float* W_out = (const float*)d_in[12];
    const float* b_out = (const float*)d_in[13];

    float* out_logits = (float*)d_out;
    float* out_h = out_logits + (size_t)BT * V;
    float* out_c = out_h + (size_t)B * H;

    char* p = (char*)d_ws;
    auto alloc = [&](size_t bytes) -> void* {
        void* r = (void*)p;
        p += (bytes + 255) & ~(size_t)255;
        return r;
    };
    f16* W_ih_h = (f16*)alloc((size_t)G4 * E * 2);
    f16* Wfrag = (f16*)alloc((size_t)NBLK * 2 * 16 * 64 * 8 * 2);  // 2MB
    f16* W_att_h = (f16*)alloc((size_t)1024 * 512 * 2);
    f16* W_comb_h = (f16*)alloc((size_t)512 * 1536 * 2);
    f16* W_out_h = (f16*)alloc((size_t)V * 512 * 2);
    f16* x_h = (f16*)alloc((size_t)BT * E * 2);
    float* gxp = (float*)alloc((size_t)T * NBLK * 32 * 32 * 4);  // 16MB
    f16* merged = (f16*)alloc((size_t)BT * 1536 * 2);
    float* qbuf = (float*)alloc((size_t)BT * 1024 * 4);
    f16* outs_h = (f16*)alloc((size_t)BT * 512 * 2);
    f16* xbuf = (f16*)alloc((size_t)2 * B * H * 2);   // exchange, block-major
    unsigned* flags = (unsigned*)alloc(256);

    // fused small preps (exact ranges) + big W_out cvt
    prep_all<<<3904, 256, 0, stream>>>(W_ih, W_ih_h, W_att, W_att_h, W_comb,
                                       W_comb_h, W_hh, Wfrag, tok, emb, x_h,
                                       h0, xbuf, flags);
    cvt_f16<<<2048, 256, 0, stream>>>(W_out, W_out_h, V * 512 / 4);

    // gates_x = x @ W_ih^T + b_ih + b_hh, written directly in permuted layout
    gemm_bt<true, true, false, true, false, float>
        <<<dim3(16, 16), 256, 0, stream>>>(x_h, E, W_ih_h, E, gxp, 0, E, b_ih,
                                           b_hh);

    // sequential LSTM (R6 structure: persistent W, flag signal + staged read)
    lstm_scan6<<<NBLK, 256, 0, stream>>>(gxp, Wfrag, c0, xbuf, flags, merged,
                                         out_h, out_c);

    // q = h_all @ W_att^T   [2048 x 1024]  (A = merged cols 0:512, lda=1536)
    gemm_bt<false, false, false, false, false, float>
        <<<dim3(8, 16), 256, 0, stream>>>(merged, 1536, W_att_h, 512, qbuf,
                                          1024, 512, nullptr, nullptr);

    // attention -> merged[:,512:1536]
    attn_apply<<<BT, 256, 0, stream>>>(qbuf, enc, merged);

    // outs = tanh(merged @ W_comb^T + b_comb)   [2048 x 512] f16
    gemm_bt<true, false, true, false, false, f16>
        <<<dim3(4, 16), 256, 0, stream>>>(merged, 1536, W_comb_h, 1536, outs_h,
                                          512, 1536, b_comb, nullptr);

    // logits = outs @ W_out^T + b_out   [2048 x 32000] fp32 -> d_out
    // MSWAP: m-tile on blockIdx.x so dispatch-adjacent blocks share W panel
    gemm_bt<true, false, false, false, true, float>
        <<<dim3(16, 250), 256, 0, stream>>>(outs_h, 512, W_out_h, 512,
                                            out_logits, V, 512, b_out,
                                            nullptr);
}

// Round 19
// 523.915 us; speedup vs baseline: 2.3025x; 1.0370x over previous
//
#include <hip/hip_runtime.h>
#include <hip/hip_fp16.h>

typedef _Float16 f16;
typedef _Float16 f16x4 __attribute__((ext_vector_type(4)));
typedef _Float16 f16x8 __attribute__((ext_vector_type(8)));
typedef float    f32x4 __attribute__((ext_vector_type(4)));
typedef unsigned long long u64t;

#define DEV __device__ __forceinline__

constexpr int B = 32, T = 64, S = 64, H = 512, E = 512, V = 32000;
constexpr int BT = B * T;      // 2048
constexpr int G4 = 4 * H;      // 2048
constexpr int NBLK = 64;       // scan blocks; each owns 8 h-units

DEV float sigf(float x) { return 1.f / (1.f + expf(-x)); }

#if defined(__has_builtin)
#if __has_builtin(__builtin_amdgcn_global_load_lds)
#define HAVE_GLL 1
#endif
#endif

// relaxed agent-scope ops: plain sc1 loads/stores, NO buffer_wbl2/inv
DEV u64t ld_u64_cg(const u64t* p) {
    return __hip_atomic_load(p, __ATOMIC_RELAXED, __HIP_MEMORY_SCOPE_AGENT);
}
DEV unsigned ld_u32_cg(const unsigned* p) {
    return __hip_atomic_load(p, __ATOMIC_RELAXED, __HIP_MEMORY_SCOPE_AGENT);
}
DEV void st_u32_cg(unsigned* p, unsigned v) {
    __hip_atomic_store(p, v, __ATOMIC_RELAXED, __HIP_MEMORY_SCOPE_AGENT);
}

#if HAVE_GLL
DEV void gll16(f16* lds, const f16* g) {
    __builtin_amdgcn_global_load_lds(
        (const __attribute__((address_space(1))) void*)g,
        (__attribute__((address_space(3))) void*)lds, 16, 0, 0);
}
#endif

// ---------------- converts / packing (R11-verified, separate kernels) ------

__global__ __launch_bounds__(256) void cvt_f16(const float* __restrict__ s,
                                               f16* __restrict__ d, int n4) {
    for (int i = blockIdx.x * blockDim.x + threadIdx.x; i < n4;
         i += gridDim.x * blockDim.x) {
        float4 v = ((const float4*)s)[i];
        f16x4 o = {(f16)v.x, (f16)v.y, (f16)v.z, (f16)v.w};
        ((f16x4*)d)[i] = o;
    }
}

// Pack W_hh [2048][512] f32 into MFMA B-fragment order, f16 (R6 layout).
__global__ __launch_bounds__(256) void pack_wfrag(const float* __restrict__ W,
                                                  f16* __restrict__ Wf) {
    int id = blockIdx.x * 256 + threadIdx.x;  // 2^17 total
    if (id >= NBLK * 2 * 16 * 64) return;
    int lane = id & 63;
    int ks = (id >> 6) & 15;
    int ni = (id >> 10) & 1;
    int n = id >> 11;
    int cl = ni * 16 + (lane & 15);
    int ul = cl >> 2, g = cl & 3;
    int unit = n * 8 + ul;
    int k = ks * 32 + (lane >> 4) * 8;
    const float* src = W + (size_t)(g * 512 + unit) * 512 + k;
    float4 a = *(const float4*)src;
    float4 b = *(const float4*)(src + 4);
    f16x8 o = {(f16)a.x, (f16)a.y, (f16)a.z, (f16)a.w,
               (f16)b.x, (f16)b.y, (f16)b.z, (f16)b.w};
    *(f16x8*)(Wf + (size_t)id * 8) = o;
}

// x[bt][e] = (f16) emb[tok[bt]][e]
__global__ __launch_bounds__(256) void gather_x(const int* __restrict__ tok,
                                                const float* __restrict__ emb,
                                                f16* __restrict__ x) {
    int id = blockIdx.x * blockDim.x + threadIdx.x;  // 2048*128
    if (id >= BT * (E / 4)) return;
    int row = id >> 7;
    int e4 = (id & 127) * 4;
    int t = tok[row];
    float4 v = *(const float4*)(emb + (size_t)t * E + e4);
    f16x4 o = {(f16)v.x, (f16)v.y, (f16)v.z, (f16)v.w};
    ((f16x4*)x)[id] = o;
}

// stage h0 into xbuf[0] (block-major layout) and reset flags (replay safe)
__global__ __launch_bounds__(256) void init_h0(const float* __restrict__ h0,
                                               f16* __restrict__ xbuf,
                                               unsigned* __restrict__ fl) {
    int i = blockIdx.x * 256 + threadIdx.x;  // 64 blocks -> 16384
    if (i < B * H) {
        int nn = i >> 8;
        int bb = (i >> 3) & 31;
        int ul = i & 7;
        xbuf[i] = (f16)h0[bb * 512 + nn * 8 + ul];
    }
    if (i < NBLK) fl[i] = 0u;
}

// ---------------- GEMM (R11-verified): C = A @ W^T (+bias, +tanh) ----------
// 128x128 tile, BK=32, 256 threads = 4 waves, mfma_f32_16x16x32_f16,
// global_load_lds staging. PERM: permuted gates output (f16). MSWAP: m-tile
// on blockIdx.x so dispatch-adjacent blocks share the W panel (logits GEMM).

template <bool BIAS, bool B2, bool TANH, bool PERM, bool MSWAP, typename OUT>
__global__ __launch_bounds__(256) void gemm_bt(
    const f16* __restrict__ A, int lda, const f16* __restrict__ W, int ldw,
    OUT* __restrict__ C, int ldc, int K, const float* __restrict__ bias1,
    const float* __restrict__ bias2) {
    __shared__ f16 smA[128 * 32];
    __shared__ f16 smB[128 * 32];
    const int tid = threadIdx.x;
    const int lane = tid & 63;
    const int wv = tid >> 6;
    const int wr = wv >> 1, wc = wv & 1;
    const int m0 = (MSWAP ? blockIdx.x : blockIdx.y) * 128;
    const int n0 = (MSWAP ? blockIdx.y : blockIdx.x) * 128;
    const int ar0 = tid >> 2;
    const int kq = (tid & 3) * 8;

    f32x4 acc[4][4];
#pragma unroll
    for (int m = 0; m < 4; m++)
#pragma unroll
        for (int n = 0; n < 4; n++) acc[m][n] = {0.f, 0.f, 0.f, 0.f};

    const int arow = wr * 64 + (lane & 15);
    const int brow = wc * 64 + (lane & 15);
    const int kk = (lane >> 4) * 8;

    const int ksteps = K >> 5;
    for (int s = 0; s < ksteps; ++s) {
        const int k0 = s * 32;
        const f16* Ag = A + (size_t)(m0 + ar0) * lda + k0 + kq;
        const f16* Wg = W + (size_t)(n0 + ar0) * ldw + k0 + kq;
#if HAVE_GLL
        __syncthreads();
        gll16(smA + wv * 512, Ag);
        gll16(smA + 2048 + wv * 512, Ag + (size_t)64 * lda);
        gll16(smB + wv * 512, Wg);
        gll16(smB + 2048 + wv * 512, Wg + (size_t)64 * ldw);
        __syncthreads();
#else
        uint4 va0 = *(const uint4*)Ag;
        uint4 va1 = *(const uint4*)(Ag + (size_t)64 * lda);
        uint4 vb0 = *(const uint4*)Wg;
        uint4 vb1 = *(const uint4*)(Wg + (size_t)64 * ldw);
        __syncthreads();
        *(uint4*)(smA + tid * 8) = va0;
        *(uint4*)(smA + (tid + 256) * 8) = va1;
        *(uint4*)(smB + tid * 8) = vb0;
        *(uint4*)(smB + (tid + 256) * 8) = vb1;
        __syncthreads();
#endif
        f16x8 af[4], bfr[4];
#pragma unroll
        for (int m = 0; m < 4; m++)
            af[m] = *(const f16x8*)(smA + (arow + m * 16) * 32 + kk);
#pragma unroll
        for (int n = 0; n < 4; n++)
            bfr[n] = *(const f16x8*)(smB + (brow + n * 16) * 32 + kk);
#pragma unroll
        for (int m = 0; m < 4; m++)
#pragma unroll
            for (int n = 0; n < 4; n++)
                acc[m][n] = __builtin_amdgcn_mfma_f32_16x16x32_f16(
                    af[m], bfr[n], acc[m][n], 0, 0, 0);
    }

    const int fr = lane & 15, fq = lane >> 4;
#pragma unroll
    for (int m = 0; m < 4; m++) {
        const int row0 = m0 + wr * 64 + m * 16 + fq * 4;
#pragma unroll
        for (int n = 0; n < 4; n++) {
            const int col = n0 + wc * 64 + n * 16 + fr;
            float bb = 0.f;
            if (BIAS) bb += bias1[col];
            if (B2) bb += bias2[col];
            int nb = 0, cl = 0;
            if (PERM) {
                int g = col >> 9;
                int unit = col & 511;
                nb = unit >> 3;
                cl = ((unit & 7) << 2) | g;
            }
#pragma unroll
            for (int r = 0; r < 4; r++) {
                float v = acc[m][n][r] + bb;
                if (TANH) v = tanhf(v);
                if (PERM) {
                    int bt = row0 + r;
                    int b_ = bt >> 6, tt = bt & 63;
                    C[((size_t)(tt * 64 + nb) * 32 + b_) * 32 + cl] = (OUT)v;
                } else {
                    C[(size_t)(row0 + r) * ldc + col] = (OUT)v;
                }
            }
        }
    }
}

// ---------------- persistent-W LSTM scan (R6/R11-verified, ~250us) ---------
// 64 blocks x 256 threads. Block n owns h-units [n*8, n*8+8).
// xbuf[2][64 n][32 bb][8 ul] f16 block-major exchange; flags[64].
// Reader: poll 64 flags (1 load/lane), ONE cooperative burst read (16 u64
// coalesced sc1 loads/thread, one MALL RTT) -> LDS hst[32][520] -> MFMA.
// Writer: h stores (sc1) -> vmcnt(0) -> syncthreads -> flag store.
// gxp is f16 (gate pre-activations, |x|~3 -> f16 safe); prefetched off the
// critical path before the flag poll. merged store after the flag.

__global__ __launch_bounds__(256, 1) void lstm_scan6(
    const f16* __restrict__ gxp, const f16* __restrict__ Wfrag,
    const float* __restrict__ c0, f16* __restrict__ xbuf,
    unsigned* __restrict__ flags, f16* __restrict__ merged,
    float* __restrict__ hout, float* __restrict__ cout) {
    const int n = blockIdx.x;
    const int tid = threadIdx.x;
    const int lane = tid & 63, wv = tid >> 6;
    const int mi = wv >> 1, ni = wv & 1;
    __shared__ f16 hst[32][520];    // staged h, +8 f16 row pad
    __shared__ float gl[32][32];

    // persistent B-fragments (the block's W_hh slice)
    f16x8 bf[16];
    const f16* wbase = Wfrag + (size_t)((n * 2 + ni) * 16) * 512 + lane * 8;
#pragma unroll
    for (int ks = 0; ks < 16; ks++) bf[ks] = *(const f16x8*)(wbase + ks * 512);

    const int bb = tid >> 3, ul = tid & 7;   // (batch, unit-local)
    const int unit = n * 8 + ul;
    float c = c0[bb * 512 + unit];
    float h = 0.f;

    const int sb = (tid & 63) >> 1;
    const int su0 = (tid & 1) * 4;
    const int arow = mi * 16 + (lane & 15);
    const int kcol0 = (lane >> 4) * 8;
    const int fr = lane & 15, fq = lane >> 4;

    for (int t = 0; t < T; ++t) {
        // prefetch this thread's 4 gate-x values (f16, 8B coalesced)
        f16x4 g4 = *(const f16x4*)(gxp +
                                   ((size_t)(t * NBLK + n) * 32 + bb) * 32 +
                                   ul * 4);
        for (;;) {
            unsigned v = ld_u32_cg(flags + lane);
            if (__all(v >= (unsigned)t)) break;
            __builtin_amdgcn_s_sleep(1);
        }
        asm volatile("" ::: "memory");  // no load hoisting above the poll
        const u64t* src = (const u64t*)(xbuf + (t & 1) * (B * H));
        u64t v[16];
#pragma unroll
        for (int i = 0; i < 16; i++) v[i] = ld_u64_cg(src + i * 256 + tid);
#pragma unroll
        for (int i = 0; i < 16; i++) {
            int np = i * 4 + wv;
            *(u64t*)(&hst[sb][np * 8 + su0]) = v[i];
        }
        __syncthreads();
        f32x4 acc0 = {0.f, 0.f, 0.f, 0.f}, acc1 = {0.f, 0.f, 0.f, 0.f};
#pragma unroll
        for (int ks = 0; ks < 16; ks++) {
            f16x8 af = *(const f16x8*)(&hst[arow][ks * 32 + kcol0]);
            if (ks & 1)
                acc1 = __builtin_amdgcn_mfma_f32_16x16x32_f16(af, bf[ks], acc1,
                                                              0, 0, 0);
            else
                acc0 = __builtin_amdgcn_mfma_f32_16x16x32_f16(af, bf[ks], acc0,
                                                              0, 0, 0);
        }
#pragma unroll
        for (int r = 0; r < 4; r++)
            gl[mi * 16 + fq * 4 + r][ni * 16 + fr] = acc0[r] + acc1[r];
        __syncthreads();
        float4 gv = *(const float4*)&gl[bb][ul * 4];
        float gi = gv.x + (float)g4.x;
        float gf = gv.y + (float)g4.y;
        float gg = gv.z + (float)g4.z;
        float go = gv.w + (float)g4.w;
        c = sigf(gf) * c + sigf(gi) * tanhf(gg);
        h = sigf(go) * tanhf(c);
        f16 hh = (f16)h;
        unsigned hv = (unsigned)__builtin_bit_cast(unsigned short, hh);
        unsigned other = (unsigned)__shfl_xor((int)hv, 1);
        f16* xn = xbuf + ((t + 1) & 1) * (B * H);
        if ((ul & 1) == 0) {
            st_u32_cg((unsigned*)(xn + n * 256 + bb * 8 + ul),
                      hv | (other << 16));
        }
        if (t < T - 1) {
            asm volatile("s_waitcnt vmcnt(0)" ::: "memory");
            __syncthreads();
            if (tid == 0) st_u32_cg(flags + n, (unsigned)(t + 1));
        } else {
            __syncthreads();
        }
        // off the critical path
        merged[(size_t)(bb * 64 + t) * 1536 + unit] = hh;
    }
    hout[bb * 512 + unit] = h;
    cout[bb * 512 + unit] = c;
}

// ---------------- fused attention (R11-verified) ----------------

__global__ __launch_bounds__(256) void attn_apply(const float* __restrict__ q,
                                                  const float* __restrict__ enc,
                                                  f16* __restrict__ merged) {
    const int bt = blockIdx.x;
    const int b = bt >> 6;
    const int tid = threadIdx.x;
    __shared__ float qs[1024];
    __shared__ float ws[64];

    const float* qrow = q + (size_t)bt * 1024;
    *(float4*)(qs + tid * 4) = *(const float4*)(qrow + tid * 4);
    __syncthreads();

    const int wv = tid >> 6, lane = tid & 63;
    const float* encb = enc + (size_t)b * S * 1024;
    for (int s = wv * 16; s < wv * 16 + 16; ++s) {
        const float* er = encb + (size_t)s * 1024;
        float p = 0.f;
#pragma unroll
        for (int i = 0; i < 16; ++i) p += qs[lane + 64 * i] * er[lane + 64 * i];
#pragma unroll
        for (int off = 32; off; off >>= 1) p += __shfl_xor(p, off);
        if (lane == 0) ws[s] = p;
    }
    __syncthreads();

    float a0 = 0.f, a1 = 0.f, a2 = 0.f, a3 = 0.f;
    for (int s = 0; s < 64; ++s) {
        float w = ws[s];
        const float* er = encb + (size_t)s * 1024;
        a0 += w * er[tid];
        a1 += w * er[tid + 256];
        a2 += w * er[tid + 512];
        a3 += w * er[tid + 768];
    }
    f16* mrow = merged + (size_t)bt * 1536 + 512;
    mrow[tid] = (f16)a0;
    mrow[tid + 256] = (f16)a1;
    mrow[tid + 512] = (f16)a2;
    mrow[tid + 768] = (f16)a3;
}

// ---------------- launcher ----------------

extern "C" void kernel_launch(void* const* d_in, const int* in_sizes, int n_in,
                              void* d_out, int out_size, void* d_ws,
                              size_t ws_size, hipStream_t stream) {
    const int* tok = (const int*)d_in[0];
    const float* enc = (const float*)d_in[1];
    const float* h0 = (const float*)d_in[2];
    const float* c0 = (const float*)d_in[3];
    const float* emb = (const float*)d_in[4];
    const float* W_ih = (const float*)d_in[5];
    const float* W_hh = (const float*)d_in[6];
    const float* b_ih = (const float*)d_in[7];
    const float* b_hh = (const float*)d_in[8];
    const float* W_att = (const float*)d_in[9];
    const float* W_comb = (const float*)d_in[10];
    const float* b_comb = (const float*)d_in[11];
    const float* W_out = (const float*)d_in[12];
    const float* b_out = (const float*)d_in[13];

    float* out_logits = (float*)d_out;
    float* out_h = out_logits + (size_t)BT * V;
    float* out_c = out_h + (size_t)B * H;

    char* p = (char*)d_ws;
    auto alloc = [&](size_t bytes) -> void* {
        void* r = (void*)p;
        p += (bytes + 255) & ~(size_t)255;
        return r;
    };
    f16* W_ih_h = (f16*)alloc((size_t)G4 * E * 2);
    f16* Wfrag = (f16*)alloc((size_t)NBLK * 2 * 16 * 64 * 8 * 2);  // 2MB
    f16* W_att_h = (f16*)alloc((size_t)1024 * 512 * 2);
    f16* W_comb_h = (f16*)alloc((size_t)512 * 1536 * 2);
    f16* W_out_h = (f16*)alloc((size_t)V * 512 * 2);
    f16* x_h = (f16*)alloc((size_t)BT * E * 2);
    f16* gxp = (f16*)alloc((size_t)T * NBLK * 32 * 32 * 2);  // 8MB, f16
    f16* merged = (f16*)alloc((size_t)BT * 1536 * 2);
    float* qbuf = (float*)alloc((size_t)BT * 1024 * 4);
    f16* outs_h = (f16*)alloc((size_t)BT * 512 * 2);
    f16* xbuf = (f16*)alloc((size_t)2 * B * H * 2);   // exchange, block-major
    unsigned* flags = (unsigned*)alloc(256);

    cvt_f16<<<512, 256, 0, stream>>>(W_ih, W_ih_h, G4 * E / 4);
    cvt_f16<<<512, 256, 0, stream>>>(W_att, W_att_h, 1024 * 512 / 4);
    cvt_f16<<<512, 256, 0, stream>>>(W_comb, W_comb_h, 512 * 1536 / 4);
    cvt_f16<<<2048, 256, 0, stream>>>(W_out, W_out_h, V * 512 / 4);
    pack_wfrag<<<512, 256, 0, stream>>>(W_hh, Wfrag);
    gather_x<<<1024, 256, 0, stream>>>(tok, emb, x_h);
    init_h0<<<64, 256, 0, stream>>>(h0, xbuf, flags);

    // gates_x = x @ W_ih^T + b_ih + b_hh, permuted layout, f16
    gemm_bt<true, true, false, true, false, f16>
        <<<dim3(16, 16), 256, 0, stream>>>(x_h, E, W_ih_h, E, gxp, 0, E, b_ih,
                                           b_hh);

    // sequential LSTM (R6 structure: persistent W, flag signal + staged read)
    lstm_scan6<<<NBLK, 256, 0, stream>>>(gxp, Wfrag, c0, xbuf, flags, merged,
                                         out_h, out_c);

    // q = h_all @ W_att^T   [2048 x 1024]  (A = merged cols 0:512, lda=1536)
    gemm_bt<false, false, false, false, false, float>
        <<<dim3(8, 16), 256, 0, stream>>>(merged, 1536, W_att_h, 512, qbuf,
                                          1024, 512, nullptr, nullptr);

    // attention -> merged[:,512:1536]
    attn_apply<<<BT, 256, 0, stream>>>(qbuf, enc, merged);

    // outs = tanh(merged @ W_comb^T + b_comb)   [2048 x 512] f16
    gemm_bt<true, false, true, false, false, f16>
        <<<dim3(4, 16), 256, 0, stream>>>(merged, 1536, W_comb_h, 1536, outs_h,
                                          512, 1536, b_comb, nullptr);

    // logits = outs @ W_out^T + b_out   [2048 x 32000] fp32 -> d_out
    // MSWAP: m-tile on blockIdx.x so dispatch-adjacent blocks share W panel
    gemm_bt<true, false, false, false, true, float>
        <<<dim3(16, 250), 256, 0, stream>>>(outs_h, 512, W_out_h, 512,
                                            out_logits, V, 512, b_out,
                                            nullptr);
}